// Round 4
// baseline (2628.758 us; speedup 1.0000x reference)
//
#include <hip/hip_runtime.h>

// simpleKT forward on gfx950: bf16 MFMA GEMMs + flash-style causal attention
// (transposed-scores formulation; P stays in registers; coalesced O epilogue;
//  XCD-aware block swizzle for K/V L2 locality).
// R4: attn_k still spills ~67MB writes at VGPR_Count=128 — launch_bounds'
//  min-waves arg only sets a MINIMUM; the backend still targeted 4 waves/SIMD
//  (128-reg granule) and spilled. Pin it: amdgpu_waves_per_eu(2,2) -> plan
//  for exactly 2 waves/SIMD, 256-reg budget, live set (~190) fits.
//  Everything else identical to R3 (64-key halves, T14 prefetch, R0 softmax).
// B=64 S=512 D=512 H=8 DK=64 L=4 DFF=2048 NSK=300 FC1=512 FC2=256.
// ENVELOPE RULE (R5-R7 postmortem): kernels use <=256 threads and <=32KB
// static LDS; no dynamic-LDS opt-in, no hipFuncSetAttribute.

typedef unsigned short u16;
typedef __attribute__((ext_vector_type(8))) short short8;   // 8 bf16 - 16x16x32 A/B frag
typedef __attribute__((ext_vector_type(4))) short short4v;  // 4 bf16 - 16x16x16 A/B frag
typedef __attribute__((ext_vector_type(4))) float f32x4;    // MFMA C/D frag

#define DEV __device__ __forceinline__

DEV float bf2f(u16 u) { return __uint_as_float(((unsigned int)u) << 16); }
DEV u16 f2bf(float f) {
  unsigned int u = __float_as_uint(f);
  u += 0x7FFFu + ((u >> 16) & 1u);
  return (u16)(u >> 16);
}

template <bool V> struct BoolC { static constexpr bool value = V; };

DEV void gl2l16(const void* g, void* l) {
  __builtin_amdgcn_global_load_lds(
      (__attribute__((address_space(1))) void*)g,
      (__attribute__((address_space(3))) void*)l, 16, 0, 0);
}

#define MFMA16(a, b, c) __builtin_amdgcn_mfma_f32_16x16x32_bf16(a, b, c, 0, 0, 0)

// 16x16x16 bf16 MFMA (K=16: k = (lane>>4)*4+j — matches C-layout rows)
#if defined(__has_builtin)
#if __has_builtin(__builtin_amdgcn_mfma_f32_16x16x16bf16_1k)
#define MFMA16X16(a, b, c) __builtin_amdgcn_mfma_f32_16x16x16bf16_1k(a, b, c, 0, 0, 0)
#elif __has_builtin(__builtin_amdgcn_mfma_f32_16x16x16_bf16)
#define MFMA16X16(a, b, c) __builtin_amdgcn_mfma_f32_16x16x16_bf16(a, b, c, 0, 0, 0)
#endif
#endif
#ifndef MFMA16X16
DEV f32x4 mfma_16x16x16_bf16_asm(short4v a, short4v b, f32x4 c) {
  f32x4 d;
  asm("v_mfma_f32_16x16x16_bf16 %0, %1, %2, %3\n\ts_nop 7\n\ts_nop 3"
      : "=&v"(d) : "v"(a), "v"(b), "v"(c));
  return d;
}
#define MFMA16X16(a, b, c) mfma_16x16x16_bf16_asm(a, b, c)
#endif

// ---------------------------------------------------------------------------
// Weight convert+transpose: fp32 [K,N] (batched over z) -> bf16 [N,K]
// ---------------------------------------------------------------------------
__global__ __launch_bounds__(256) void transpose_cvt(
    const float* __restrict__ src, u16* __restrict__ dst, int K, int N)
{
  src += (size_t)blockIdx.z * K * N;
  dst += (size_t)blockIdx.z * K * N;
  __shared__ alignas(16) float tile[32][33];
  const int tx = threadIdx.x & 31, ty = threadIdx.x >> 5;
  const int n0 = blockIdx.x * 32, k0 = blockIdx.y * 32;
#pragma unroll
  for (int i = 0; i < 4; ++i) {
    int k = k0 + ty + i * 8, n = n0 + tx;
    if (k < K && n < N) tile[ty + i * 8][tx] = src[(size_t)k * N + n];
  }
  __syncthreads();
#pragma unroll
  for (int i = 0; i < 4; ++i) {
    int n = n0 + ty + i * 8, k = k0 + tx;
    if (n < N && k < K) dst[(size_t)n * K + k] = f2bf(tile[tx][ty + i * 8]);
  }
}

// ---------------------------------------------------------------------------
// Embedding: x = q_emb[q_data] + pe[s]; y = qa_emb[target] + q_emb[q_data] + pe[s]
// ---------------------------------------------------------------------------
__global__ __launch_bounds__(256) void embed_k(
    const int* __restrict__ qd, const int* __restrict__ tg,
    const float* __restrict__ pe, const float* __restrict__ qe, const float* __restrict__ qa,
    u16* __restrict__ x_b, u16* __restrict__ y_b)
{
  const int row = blockIdx.x * 4 + (threadIdx.x >> 6);
  const int lane = threadIdx.x & 63;
  const int s = row & 511;
  const int idx = qd[row];
  const int tt = tg[row];
  const int c = lane * 8;
  const float* q = qe + (size_t)idx * 512 + c;
  const float* p = pe + (size_t)s * 512 + c;
  const float* a = qa + (size_t)tt * 512 + c;
  float4 q0 = *(const float4*)q, q1 = *(const float4*)(q + 4);
  float4 p0 = *(const float4*)p, p1 = *(const float4*)(p + 4);
  float4 a0 = *(const float4*)a, a1 = *(const float4*)(a + 4);
  float qv[8] = {q0.x, q0.y, q0.z, q0.w, q1.x, q1.y, q1.z, q1.w};
  float pv[8] = {p0.x, p0.y, p0.z, p0.w, p1.x, p1.y, p1.z, p1.w};
  float av[8] = {a0.x, a0.y, a0.z, a0.w, a1.x, a1.y, a1.z, a1.w};
  short8 ox, oy;
#pragma unroll
  for (int i = 0; i < 8; ++i) {
    ox[i] = (short)f2bf(qv[i] + pv[i]);
    oy[i] = (short)f2bf(qv[i] + pv[i] + av[i]);
  }
  size_t base = (size_t)row * 512 + c;
  *(short8*)(x_b + base) = ox;
  *(short8*)(y_b + base) = oy;
}

// ---------------------------------------------------------------------------
// bf16 GEMM core (m97 structure): C[M,N] = act(A[M,K] @ Bt[N,K]^T + bias)
// 128x128 tile, BK=32, 256 thr. OUTM: 0 = bf16 row-major, 1 = f32 row-major,
// 2 = bf16 scatter into vT[b,h,dk,s].  (compile-time epilogue)
// ---------------------------------------------------------------------------
template <int ACT, int OUTM>
DEV void gemm_core(u16* As, u16* Bs,
                   const u16* __restrict__ A, const u16* __restrict__ Bt,
                   const float* __restrict__ bias, void* __restrict__ Cv,
                   int M, int N, int K, int bx, int by)
{
  const int lane = threadIdx.x & 63;
  const int w = threadIdx.x >> 6;
  const int wm = w >> 1, wn = w & 1;
  const int m0 = by * 128, n0 = bx * 128;

  const u16* pa[2];
  const u16* pb[2];
  u16* la[2];
  u16* lb[2];
#pragma unroll
  for (int i = 0; i < 2; ++i) {
    int tb = w * 2 + i;
    int r = tb * 16 + (lane >> 2);
    int ps = (lane & 3) ^ ((r >> 1) & 3);
    pa[i] = A + (size_t)(m0 + r) * K + ps * 8;
    int rb = n0 + r;
    rb = (rb < N) ? rb : (N - 1);
    pb[i] = Bt + (size_t)rb * K + ps * 8;
    la[i] = As + (tb * 64 + lane) * 8;
    lb[i] = Bs + (tb * 64 + lane) * 8;
  }
  const u16* ra[4];
  const u16* rbp[4];
#pragma unroll
  for (int i = 0; i < 4; ++i) {
    int r = wm * 64 + i * 16 + (lane & 15);
    ra[i] = As + (r * 4 + ((lane >> 4) ^ ((r >> 1) & 3))) * 8;
    int r2 = wn * 64 + i * 16 + (lane & 15);
    rbp[i] = Bs + (r2 * 4 + ((lane >> 4) ^ ((r2 >> 1) & 3))) * 8;
  }

  f32x4 acc[4][4];
#pragma unroll
  for (int a_ = 0; a_ < 4; ++a_)
#pragma unroll
    for (int b_ = 0; b_ < 4; ++b_)
#pragma unroll
      for (int i = 0; i < 4; ++i) acc[a_][b_][i] = 0.f;

  for (int k0 = 0; k0 < K; k0 += 32) {
    gl2l16(pa[0], la[0]);
    gl2l16(pa[1], la[1]);
    gl2l16(pb[0], lb[0]);
    gl2l16(pb[1], lb[1]);
    pa[0] += 32; pa[1] += 32; pb[0] += 32; pb[1] += 32;
    __syncthreads();
    short8 af[4], bf[4];
#pragma unroll
    for (int i = 0; i < 4; ++i) af[i] = *(const short8*)ra[i];
#pragma unroll
    for (int i = 0; i < 4; ++i) bf[i] = *(const short8*)rbp[i];
#pragma unroll
    for (int mt = 0; mt < 4; ++mt)
#pragma unroll
      for (int nt = 0; nt < 4; ++nt)
        acc[mt][nt] = MFMA16(af[mt], bf[nt], acc[mt][nt]);
    __syncthreads();
  }

  const int row0 = m0 + wm * 64, col0 = n0 + wn * 64;
#pragma unroll
  for (int mt = 0; mt < 4; ++mt) {
#pragma unroll
    for (int nt = 0; nt < 4; ++nt) {
      int c = col0 + nt * 16 + (lane & 15);
      int r = row0 + mt * 16 + (lane >> 4) * 4;
      if (c < N) {
        float bz = bias[c];
#pragma unroll
        for (int i = 0; i < 4; ++i) {
          float v = acc[mt][nt][i] + bz;
          if (ACT == 1) v = fmaxf(v, 0.f);
          int m = r + i;
          if (OUTM == 0) {
            ((u16*)Cv)[(size_t)m * N + c] = f2bf(v);
          } else if (OUTM == 1) {
            ((float*)Cv)[(size_t)m * N + c] = v;
          } else {  // vT[b][h][dk][s]: m=(b,s) local, c=(h,dk)
            size_t idx = ((((size_t)(m >> 9)) * 8 + (c >> 6)) * 64 + (c & 63)) * 512 + (m & 511);
            ((u16*)Cv)[idx] = f2bf(v);
          }
        }
      }
    }
  }
}

template <int ACT, int OUTM>
__global__ __launch_bounds__(256) void gemm_bt(
    const u16* __restrict__ A, const u16* __restrict__ Bt,
    const float* __restrict__ bias, void* __restrict__ Cv,
    int M, int N, int K)
{
  __shared__ alignas(16) u16 As[128 * 32];
  __shared__ alignas(16) u16 Bs[128 * 32];
  gemm_core<ACT, OUTM>(As, Bs, A, Bt, bias, Cv, M, N, K, blockIdx.x, blockIdx.y);
}

// fused K/V projection: z=0 -> x@Wk -> s_kq (OUTM 0); z=1 -> y@Wv -> vT (OUTM 2)
__global__ __launch_bounds__(256) void gemm_kv(
    const u16* __restrict__ A0, const u16* __restrict__ Bt0,
    const float* __restrict__ b0, void* __restrict__ C0,
    const u16* __restrict__ A1, const u16* __restrict__ Bt1,
    const float* __restrict__ b1, void* __restrict__ C1,
    int M, int N, int K)
{
  __shared__ alignas(16) u16 As[128 * 32];
  __shared__ alignas(16) u16 Bs[128 * 32];
  if (blockIdx.z == 0)
    gemm_core<0, 0>(As, Bs, A0, Bt0, b0, C0, M, N, K, blockIdx.x, blockIdx.y);
  else
    gemm_core<0, 2>(As, Bs, A1, Bt1, b1, C1, M, N, K, blockIdx.x, blockIdx.y);
}

// ---------------------------------------------------------------------------
// Flash attention, transposed scores. grid (qtile=4, h=8, b=NB), 256 thr.
// XCD-aware swizzle: linear block id l -> (t, bh) such that the 4 q-tiles of
// one (b,h) share l%8 (same XCD under round-robin dispatch) -> K/V L2 hits.
// Wave w owns q-cols [w*32, w*32+32). S^T = K Q^T via 16x16x32 (keys=M, q=N);
// C-layout: q = lane&15 (col), key = (lane>>4)*4+i (row). P^T stays in regs as
// 16x16x16 B-frags; O^T = V^T P^T with dk as M.
// Pipeline (T14): K/V chunk j+1 is global_load'ed into VGPRs while chunk j
// computes; ds_write_b128 at loop top. Each chunk is processed as TWO 64-key
// halves with their own online-softmax update (spill fix, R3). Softmax math
// = R0 (scaled-domain mask/max, plain-subtract exp2 -> fully-masked rows
// give exp2(0)=1 benignly, neutralized by the qg>0 epilogue guard).
// Epilogue bounces O^T through wave-private LDS (XOR swizzle) for coalesced
// short8 stores. LDS 32KB.
// amdgpu_waves_per_eu(2,2): pin the allocator's occupancy target at 2
// waves/SIMD (256-reg budget). R3 evidence: launch_bounds(256,2) is only a
// MINIMUM -> backend still aimed for 4 waves/SIMD (VGPR_Count=128) and
// spilled ~67MB/dispatch (WRITE 101MB vs 33.5MB ideal O traffic).
// ---------------------------------------------------------------------------
__attribute__((amdgpu_waves_per_eu(2, 2)))
__global__ __launch_bounds__(256) void attn_k(
    const u16* __restrict__ kq, const u16* __restrict__ vT, u16* __restrict__ o)
{
  __shared__ alignas(16) u16 Ks[128 * 64];
  __shared__ alignas(16) u16 Vs[64 * 128];
  // bijective swizzle of the linear id: bits[2:0]+bits[10:5] pick (b,h);
  // bits[4:3] pick q-tile -> same (b,h) stays on one XCD (l%8 fixed).
  const int l = blockIdx.x + 4 * (blockIdx.y + 8 * blockIdx.z);
  const int t = 3 - ((l >> 3) & 3);   // long q-tiles first -> better makespan
  const int bh = (l & 7) + 8 * (l >> 5);
  const int h = bh & 7, b = bh >> 3;
  const int lane = threadIdx.x & 63;
  const int w = threadIdx.x >> 6;
  const int q0 = t * 128;
  const size_t kq_base = ((size_t)b * 512) * 512 + h * 64;
  const float SC = 0.125f * 1.44269504089f;  // scale * log2(e): softmax in exp2 domain

  // stage Q tile [128 x 64] into Ks (direct-to-LDS; one-shot)
#pragma unroll
  for (int i = 0; i < 4; ++i) {
    int tb = w * 4 + i;
    int r = tb * 8 + (lane >> 3);
    int ps = (lane & 7) ^ (r & 7);
    gl2l16(kq + kq_base + (size_t)(q0 + r) * 512 + ps * 8, Ks + (tb * 64 + lane) * 8);
  }

  // K/V chunk staging addresses (reg-staged; same swizzled layout as gl2l16:
  // wave-uniform base + lane*16B)
  const u16* gK[4];
  const u16* gV[4];
  u16* lK[4];
  u16* lV[4];
#pragma unroll
  for (int i = 0; i < 4; ++i) {
    int tb = w * 4 + i;
    int rk = tb * 8 + (lane >> 3);
    int pk = (lane & 7) ^ (rk & 7);
    gK[i] = kq + kq_base + (size_t)rk * 512 + pk * 8;
    lK[i] = Ks + (tb * 64 + lane) * 8;
    int rv = tb * 4 + (lane >> 4);
    int pv = (lane & 15) ^ (rv & 15);
    gV[i] = vT + ((size_t)((b * 8 + h) * 64 + rv)) * 512 + pv * 8;
    lV[i] = Vs + (tb * 64 + lane) * 8;
  }

  // prologue: chunk-0 K/V loads fly while the Q-stage barrier drains
  short8 rgK[4], rgV[4];
#pragma unroll
  for (int i = 0; i < 4; ++i) rgK[i] = *(const short8*)gK[i];
#pragma unroll
  for (int i = 0; i < 4; ++i) rgV[i] = *(const short8*)gV[i];

  __syncthreads();
  short8 qf[2][2];
#pragma unroll
  for (int nt = 0; nt < 2; ++nt)
#pragma unroll
    for (int ks = 0; ks < 2; ++ks) {
      int q = w * 32 + nt * 16 + (lane & 15);
      int ch = ks * 4 + (lane >> 4);
      qf[nt][ks] = *(const short8*)(Ks + (q * 8 + (ch ^ (q & 7))) * 8);
    }

  f32x4 of[4][2];  // [dk-tile][q-tile]; col=q=lane&15, row=dk=(lane>>4)*4+i
  float m_st[2] = {-1e30f, -1e30f}, l_st[2] = {0.f, 0.f};  // scaled domain
#pragma unroll
  for (int d = 0; d < 4; ++d)
#pragma unroll
    for (int nt = 0; nt < 2; ++nt)
#pragma unroll
      for (int i = 0; i < 4; ++i) of[d][nt][i] = 0.f;

  auto chunk = [&](int j, auto diagc) {
    constexpr bool DIAG = decltype(diagc)::value;
    // diagonal chunk: wave w needs keys < w*32+32 -> key-tiles mt < 2w+2
    const int MT = DIAG ? (2 * w + 2) : 8;
    const int k0 = j * 128;

    // two 64-key halves, each with its own online-softmax update: halves the
    // sc/pf live range (32+16 regs instead of 64+32) -> no spill at 256-reg
    // budget. Extra cost: one of-rescale + 2 shuffle-reduces per chunk.
#pragma unroll
    for (int hh = 0; hh < 2; ++hh) {
      if (!DIAG || MT > hh * 4) {
        const int MTl = DIAG ? ((MT - hh * 4 < 4) ? MT - hh * 4 : 4) : 4;

        // S^T = K Q^T (this half's 4 key-tiles)
        f32x4 sc[4][2];
        __builtin_amdgcn_s_setprio(1);
#pragma unroll
        for (int mt = 0; mt < 4; ++mt)
          if (!DIAG || mt < MTl) {
#pragma unroll
            for (int nt = 0; nt < 2; ++nt)
#pragma unroll
              for (int i = 0; i < 4; ++i) sc[mt][nt][i] = 0.f;
#pragma unroll
            for (int ks = 0; ks < 2; ++ks) {
              int key = (hh * 4 + mt) * 16 + (lane & 15);
              int ch = ks * 4 + (lane >> 4);
              short8 kf = *(const short8*)(Ks + (key * 8 + (ch ^ (key & 7))) * 8);
              sc[mt][0] = MFMA16(kf, qf[0][ks], sc[mt][0]);
              sc[mt][1] = MFMA16(kf, qf[1][ks], sc[mt][1]);
            }
          }
        __builtin_amdgcn_s_setprio(0);

        // scale into log2 domain + strict causal mask (diag chunk only)
#pragma unroll
        for (int mt = 0; mt < 4; ++mt)
          if (!DIAG || mt < MTl) {
#pragma unroll
            for (int nt = 0; nt < 2; ++nt) {
              int qg = q0 + w * 32 + nt * 16 + (lane & 15);
#pragma unroll
              for (int i = 0; i < 4; ++i) {
                int kg = k0 + (hh * 4 + mt) * 16 + (lane >> 4) * 4 + i;
                float v = sc[mt][nt][i] * SC;
                if (DIAG && kg >= qg) v = -1e30f;
                sc[mt][nt][i] = v;
              }
            }
          }

        // online softmax (exp2 domain): per-lane scalar state (q = lane&15)
        short4v pf[4][2];
#pragma unroll
        for (int nt = 0; nt < 2; ++nt) {
          float mx = -1e30f;
#pragma unroll
          for (int mt = 0; mt < 4; ++mt)
            if (!DIAG || mt < MTl) {
#pragma unroll
              for (int i = 0; i < 4; ++i) mx = fmaxf(mx, sc[mt][nt][i]);
            }
          mx = fmaxf(mx, __shfl_xor(mx, 16));
          mx = fmaxf(mx, __shfl_xor(mx, 32));
          float mo = m_st[nt];
          float mn = fmaxf(mo, mx);
          float al = exp2f(mo - mn);
          float rs = 0.f;
#pragma unroll
          for (int mt = 0; mt < 4; ++mt)
            if (!DIAG || mt < MTl) {
#pragma unroll
              for (int i = 0; i < 4; ++i) {
                float pv = exp2f(sc[mt][nt][i] - mn);
                sc[mt][nt][i] = pv;
                rs += pv;
              }
            }
          rs += __shfl_xor(rs, 16);
          rs += __shfl_xor(rs, 32);
          m_st[nt] = mn;
          l_st[nt] = l_st[nt] * al + rs;
#pragma unroll
          for (int d = 0; d < 4; ++d)
#pragma unroll
            for (int i = 0; i < 4; ++i) of[d][nt][i] *= al;
          // pack P^T to bf16 16x16x16 B-frags (k = (lane>>4)*4+i)
#pragma unroll
          for (int mt = 0; mt < 4; ++mt)
            if (!DIAG || mt < MTl) {
#pragma unroll
              for (int i = 0; i < 4; ++i) pf[mt][nt][i] = (short)f2bf(sc[mt][nt][i]);
            }
        }

        // O^T += V^T P^T  (A = V^T frag: m=dk, k=key; 16x16x16)
        __builtin_amdgcn_s_setprio(1);
#pragma unroll
        for (int mt = 0; mt < 4; ++mt)
          if (!DIAG || mt < MTl) {
            int key4 = (hh * 4 + mt) * 16 + (lane >> 4) * 4;
#pragma unroll
            for (int d = 0; d < 4; ++d) {
              int dk = d * 16 + (lane & 15);
              short4v vf = *(const short4v*)(
                  Vs + (dk * 16 + ((key4 >> 3) ^ (dk & 15))) * 8 + (key4 & 7));
              of[d][0] = MFMA16X16(vf, pf[mt][0], of[d][0]);
              of[d][1] = MFMA16X16(vf, pf[mt][1], of[d][1]);
            }
          }
        __builtin_amdgcn_s_setprio(0);
      }
    }
  };

  for (int j = 0; j <= t; ++j) {
    __syncthreads();  // all waves done reading chunk j-1 LDS (and qf at j=0)
#pragma unroll
    for (int i = 0; i < 4; ++i) *(short8*)lK[i] = rgK[i];  // vmcnt wait lands
#pragma unroll
    for (int i = 0; i < 4; ++i) *(short8*)lV[i] = rgV[i];  // here, post-compute
    __syncthreads();
    if (j < t) {
      // issue chunk j+1 loads; latency hides under chunk j compute
      const size_t ko = (size_t)(j + 1) * 128;
#pragma unroll
      for (int i = 0; i < 4; ++i) rgK[i] = *(const short8*)(gK[i] + ko * 512);
#pragma unroll
      for (int i = 0; i < 4; ++i) rgV[i] = *(const short8*)(gV[i] + ko);
      chunk(j, BoolC<false>{});
    } else {
      chunk(j, BoolC<true>{});
    }
  }

  // epilogue: O^T -> wave-private LDS (swizzled) -> coalesced row-major stores
  __syncthreads();  // all waves done reading Ks/Vs
  u16* Ws = Ks + w * 2048;  // 32 q-rows x 64 dk per wave
#pragma unroll
  for (int nt = 0; nt < 2; ++nt) {
    int qrow = nt * 16 + (lane & 15);
    int qg = q0 + w * 32 + qrow;
    float li = l_st[nt];
    float inv = (qg > 0 && li > 0.f) ? (1.f / li) : 0.f;
    int sw = (qrow & 7) * 8;
#pragma unroll
    for (int d = 0; d < 4; ++d)
#pragma unroll
      for (int i = 0; i < 4; ++i) {
        int dk = d * 16 + (lane >> 4) * 4 + i;
        Ws[qrow * 64 + (dk ^ sw)] = f2bf(of[d][nt][i] * inv);
      }
  }
  // wave-private: no barrier needed (lgkmcnt ordering within wave)
#pragma unroll
  for (int p = 0; p < 4; ++p) {
    int qrow = p * 8 + (lane >> 3);
    int c = lane & 7;
    short8 vv = *(const short8*)(Ws + qrow * 64 + ((c ^ (qrow & 7)) * 8));
    int qg = q0 + w * 32 + qrow;
    *(short8*)(o + ((size_t)b * 512 + qg) * 512 + h * 64 + c * 8) = vv;
  }
}

// ---------------------------------------------------------------------------
// LayerNorm(x + res); one wave per 512-col row; in-place safe.
// ---------------------------------------------------------------------------
__global__ __launch_bounds__(256) void ln_res(
    const u16* __restrict__ xin, const u16* __restrict__ res,
    const float* __restrict__ gam, const float* __restrict__ bet, u16* __restrict__ xout)
{
  const int row = blockIdx.x * 4 + (threadIdx.x >> 6);
  const int lane = threadIdx.x & 63;
  const size_t base = (size_t)row * 512 + lane * 8;
  short8 xv = *(const short8*)(xin + base);
  short8 rv = *(const short8*)(res + base);
  float v[8];
  float s = 0.f, s2 = 0.f;
#pragma unroll
  for (int i = 0; i < 8; ++i) {
    float a = bf2f((u16)xv[i]) + bf2f((u16)rv[i]);
    v[i] = a;
    s += a;
    s2 += a * a;
  }
#pragma unroll
  for (int d = 1; d < 64; d <<= 1) {
    s += __shfl_xor(s, d);
    s2 += __shfl_xor(s2, d);
  }
  float mean = s * (1.f / 512.f);
  float var = s2 * (1.f / 512.f) - mean * mean;
  float rstd = rsqrtf(var + 1e-5f);
  const int c = lane * 8;
  short8 ov;
#pragma unroll
  for (int i = 0; i < 8; ++i) {
    float ot = (v[i] - mean) * rstd * gam[c + i] + bet[c + i];
    ov[i] = (short)f2bf(ot);
  }
  *(short8*)(xout + base) = ov;
}

// ---------------------------------------------------------------------------
// concat [x, q_emb[q_data]] -> cat [rows,1024] bf16
// ---------------------------------------------------------------------------
__global__ __launch_bounds__(256) void concat2_k(
    const u16* __restrict__ x, const int* __restrict__ qd,
    const float* __restrict__ qemb, u16* __restrict__ cat)
{
  const int row = blockIdx.x * 4 + (threadIdx.x >> 6);
  const int lane = threadIdx.x & 63;
  *(short8*)(cat + (size_t)row * 1024 + lane * 8) =
      *(const short8*)(x + (size_t)row * 512 + lane * 8);
  const int idx = qd[row];
  const float* q = qemb + (size_t)idx * 512 + lane * 8;
  float4 q0 = *(const float4*)q, q1 = *(const float4*)(q + 4);
  float qv[8] = {q0.x, q0.y, q0.z, q0.w, q1.x, q1.y, q1.z, q1.w};
  short8 ov;
#pragma unroll
  for (int i = 0; i < 8; ++i) ov[i] = (short)f2bf(qv[i]);
  *(short8*)(cat + (size_t)row * 1024 + 512 + lane * 8) = ov;
}

// ---------------------------------------------------------------------------
extern "C" void kernel_launch(void* const* d_in, const int* in_sizes, int n_in,
                              void* d_out, int out_size, void* d_ws, size_t ws_size,
                              hipStream_t stream)
{
  const int* qd = (const int*)d_in[0];
  const int* tg = (const int*)d_in[1];
  const float* pe = (const float*)d_in[2];
  const float* qemb = (const float*)d_in[3];
  const float* qa = (const float*)d_in[4];
  const float* Wk = (const float*)d_in[5];
  const float* bk = (const float*)d_in[6];
  const float* Wv = (const float*)d_in[7];
  const float* bv = (const float*)d_in[8];
  const float* Wo = (const float*)d_in[9];
  const float* bo = (const float*)d_in[10];
  const float* g1 = (const float*)d_in[11];
  const float* be1 = (const float*)d_in[12];
  const float* W1 = (const float*)d_in[13];
  const float* b1 = (const float*)d_in[14];
  const float* W2 = (const float*)d_in[15];
  const float* b2 = (const float*)d_in[16];
  const float* g2 = (const float*)d_in[17];
  const float* be2 = (const float*)d_in[18];
  const float* Wo1 = (const float*)d_in[19];
  const float* bo1 = (const float*)d_in[20];
  const float* Wo2 = (const float*)d_in[21];
  const float* bo2 = (const float*)d_in[22];
  const float* Wo3 = (const float*)d_in[23];
  const float* bo3 = (const float*)d_in[24];
  float* out = (float*)d_out;

  const int BS = 64 * 512;  // 32768

  // batch-group chunking from ws_size (constant per process -> graph-safe)
  const size_t WU16 = 12266496ull;
  int NC = 1;
  {
    auto need = [&](int nc) -> size_t {
      size_t CMr = (size_t)BS / nc;
      size_t st = CMr < 8192 ? CMr : 8192;
      return 2ull * (WU16 + 2ull * BS * 512 + 3ull * CMr * 512 + st * 2048);
    };
    if (ws_size < need(1)) NC = 4;
    if (NC == 4 && ws_size < need(4)) NC = 8;
  }
  const int CM = BS / NC;
  const int MI = CM < 8192 ? CM : 8192;

  u16* p = (u16*)d_ws;
  u16* wkT = p;  p += 4 * 512 * 512;
  u16* wvT = p;  p += 4 * 512 * 512;
  u16* woT = p;  p += 4 * 512 * 512;
  u16* w1T = p;  p += 4 * 512 * 2048;
  u16* w2T = p;  p += 4 * 2048 * 512;
  u16* wo1T = p; p += 1024 * 512;
  u16* wo2T = p; p += 512 * 256;
  u16* wo3T = p; p += 300 * 256;
  u16* x_b = p;  p += (size_t)BS * 512;
  u16* y_b = p;  p += (size_t)BS * 512;
  u16* s_kq = p; p += (size_t)CM * 512;   // also head-cat first half
  u16* s_vT = p; p += (size_t)CM * 512;   // adjacent: cat = s_kq[CM x 1024]
  u16* s_o = p;  p += (size_t)CM * 512;
  u16* s_t = p;                            // MI x 2048 FFN / head scratch

  transpose_cvt<<<dim3(16, 16, 4), 256, 0, stream>>>(Wk, wkT, 512, 512);
  transpose_cvt<<<dim3(16, 16, 4), 256, 0, stream>>>(Wv, wvT, 512, 512);
  transpose_cvt<<<dim3(16, 16, 4), 256, 0, stream>>>(Wo, woT, 512, 512);
  transpose_cvt<<<dim3(64, 16, 4), 256, 0, stream>>>(W1, w1T, 512, 2048);
  transpose_cvt<<<dim3(16, 64, 4), 256, 0, stream>>>(W2, w2T, 2048, 512);
  transpose_cvt<<<dim3(16, 32, 1), 256, 0, stream>>>(Wo1, wo1T, 1024, 512);
  transpose_cvt<<<dim3(8, 16, 1), 256, 0, stream>>>(Wo2, wo2T, 512, 256);
  transpose_cvt<<<dim3(10, 8, 1), 256, 0, stream>>>(Wo3, wo3T, 256, 300);

  embed_k<<<BS / 4, 256, 0, stream>>>(qd, tg, pe, qemb, qa, x_b, y_b);

  for (int l = 0; l < 4; ++l) {
    const size_t lw = (size_t)l * 512 * 512;
    for (int cc = 0; cc < NC; ++cc) {
      const size_t R = (size_t)cc * CM;
      // fused q/k + v projections (kq_same=1)
      gemm_kv<<<dim3(4, CM / 128, 2), 256, 0, stream>>>(
          x_b + R * 512, wkT + lw, bk + l * 512, s_kq,
          y_b + R * 512, wvT + lw, bv + l * 512, s_vT, CM, 512, 512);
      attn_k<<<dim3(4, 8, CM / 512), 256, 0, stream>>>(s_kq, s_vT, s_o);
      gemm_bt<0, 0><<<dim3(4, CM / 128), 256, 0, stream>>>(
          s_o, woT + lw, bo + l * 512, s_kq, CM, 512, 512);
      ln_res<<<CM / 4, 256, 0, stream>>>(
          x_b + R * 512, s_kq, g1 + l * 512, be1 + l * 512, x_b + R * 512);
      for (int mc = 0; mc < CM; mc += MI) {
        gemm_bt<1, 0><<<dim3(16, MI / 128), 256, 0, stream>>>(
            x_b + (R + mc) * 512, w1T + (size_t)l * 512 * 2048, b1 + l * 2048,
            s_t, MI, 2048, 512);
        gemm_bt<0, 0><<<dim3(4, MI / 128), 256, 0, stream>>>(
            s_t, w2T + (size_t)l * 2048 * 512, b2 + l * 512,
            s_vT + (size_t)mc * 512, MI, 512, 2048);
      }
      ln_res<<<CM / 4, 256, 0, stream>>>(
          x_b + R * 512, s_vT, g2 + l * 512, be2 + l * 512, x_b + R * 512);
    }
  }

  for (int cc = 0; cc < NC; ++cc) {
    const size_t R = (size_t)cc * CM;
    concat2_k<<<CM / 4, 256, 0, stream>>>(x_b + R * 512, qd + R, qemb, s_kq);
    gemm_bt<1, 0><<<dim3(4, CM / 128), 256, 0, stream>>>(
        s_kq, wo1T, bo1, s_o, CM, 512, 1024);
    gemm_bt<1, 0><<<dim3(2, CM / 128), 256, 0, stream>>>(
        s_o, wo2T, bo2, s_t, CM, 256, 512);
    gemm_bt<0, 1><<<dim3(3, CM / 128), 256, 0, stream>>>(
        s_t, wo3T, bo3, out + R * 300, CM, 300, 256);
  }
}

// Round 5
// 2491.275 us; speedup vs baseline: 1.0552x; 1.0552x over previous
//
#include <hip/hip_runtime.h>

// simpleKT forward on gfx950: bf16 MFMA GEMMs + flash-style causal attention
// (transposed-scores formulation; P stays in registers; coalesced O epilogue;
//  XCD-aware block swizzle for K/V L2 locality).
// R5: kill the remaining attn_k spill by DEMAND reduction. Evidence trail:
//  (256,3)->84 VGPR, (256,2)->128, +waves_per_eu(2,2)->128 (no-op): the
//  allocator picks its own target and spills overflow; attributes can't
//  raise it. Live-set audit: of32+qf16+sc32+pf16+prefetch32+ptrs24+misc15
//  ~165 vs 128 -> ~40 spilled regs = the 110MB scratch traffic. Fix: drop
//  the T14 reg-staged prefetch (never showed benefit; 56 regs of the
//  overflow) and stage K/V via global_load_lds as in R0. Demand ~116 < 128.
//  Keeps R3's 64-key halves, DIAG split, setprio, R0 softmax numerics.
// B=64 S=512 D=512 H=8 DK=64 L=4 DFF=2048 NSK=300 FC1=512 FC2=256.
// ENVELOPE RULE (R5-R7 postmortem): kernels use <=256 threads and <=32KB
// static LDS; no dynamic-LDS opt-in, no hipFuncSetAttribute.

typedef unsigned short u16;
typedef __attribute__((ext_vector_type(8))) short short8;   // 8 bf16 - 16x16x32 A/B frag
typedef __attribute__((ext_vector_type(4))) short short4v;  // 4 bf16 - 16x16x16 A/B frag
typedef __attribute__((ext_vector_type(4))) float f32x4;    // MFMA C/D frag

#define DEV __device__ __forceinline__

DEV float bf2f(u16 u) { return __uint_as_float(((unsigned int)u) << 16); }
DEV u16 f2bf(float f) {
  unsigned int u = __float_as_uint(f);
  u += 0x7FFFu + ((u >> 16) & 1u);
  return (u16)(u >> 16);
}

template <bool V> struct BoolC { static constexpr bool value = V; };

DEV void gl2l16(const void* g, void* l) {
  __builtin_amdgcn_global_load_lds(
      (__attribute__((address_space(1))) void*)g,
      (__attribute__((address_space(3))) void*)l, 16, 0, 0);
}

#define MFMA16(a, b, c) __builtin_amdgcn_mfma_f32_16x16x32_bf16(a, b, c, 0, 0, 0)

// 16x16x16 bf16 MFMA (K=16: k = (lane>>4)*4+j — matches C-layout rows)
#if defined(__has_builtin)
#if __has_builtin(__builtin_amdgcn_mfma_f32_16x16x16bf16_1k)
#define MFMA16X16(a, b, c) __builtin_amdgcn_mfma_f32_16x16x16bf16_1k(a, b, c, 0, 0, 0)
#elif __has_builtin(__builtin_amdgcn_mfma_f32_16x16x16_bf16)
#define MFMA16X16(a, b, c) __builtin_amdgcn_mfma_f32_16x16x16_bf16(a, b, c, 0, 0, 0)
#endif
#endif
#ifndef MFMA16X16
DEV f32x4 mfma_16x16x16_bf16_asm(short4v a, short4v b, f32x4 c) {
  f32x4 d;
  asm("v_mfma_f32_16x16x16_bf16 %0, %1, %2, %3\n\ts_nop 7\n\ts_nop 3"
      : "=&v"(d) : "v"(a), "v"(b), "v"(c));
  return d;
}
#define MFMA16X16(a, b, c) mfma_16x16x16_bf16_asm(a, b, c)
#endif

// ---------------------------------------------------------------------------
// Weight convert+transpose: fp32 [K,N] (batched over z) -> bf16 [N,K]
// ---------------------------------------------------------------------------
__global__ __launch_bounds__(256) void transpose_cvt(
    const float* __restrict__ src, u16* __restrict__ dst, int K, int N)
{
  src += (size_t)blockIdx.z * K * N;
  dst += (size_t)blockIdx.z * K * N;
  __shared__ alignas(16) float tile[32][33];
  const int tx = threadIdx.x & 31, ty = threadIdx.x >> 5;
  const int n0 = blockIdx.x * 32, k0 = blockIdx.y * 32;
#pragma unroll
  for (int i = 0; i < 4; ++i) {
    int k = k0 + ty + i * 8, n = n0 + tx;
    if (k < K && n < N) tile[ty + i * 8][tx] = src[(size_t)k * N + n];
  }
  __syncthreads();
#pragma unroll
  for (int i = 0; i < 4; ++i) {
    int n = n0 + ty + i * 8, k = k0 + tx;
    if (n < N && k < K) dst[(size_t)n * K + k] = f2bf(tile[tx][ty + i * 8]);
  }
}

// ---------------------------------------------------------------------------
// Embedding: x = q_emb[q_data] + pe[s]; y = qa_emb[target] + q_emb[q_data] + pe[s]
// ---------------------------------------------------------------------------
__global__ __launch_bounds__(256) void embed_k(
    const int* __restrict__ qd, const int* __restrict__ tg,
    const float* __restrict__ pe, const float* __restrict__ qe, const float* __restrict__ qa,
    u16* __restrict__ x_b, u16* __restrict__ y_b)
{
  const int row = blockIdx.x * 4 + (threadIdx.x >> 6);
  const int lane = threadIdx.x & 63;
  const int s = row & 511;
  const int idx = qd[row];
  const int tt = tg[row];
  const int c = lane * 8;
  const float* q = qe + (size_t)idx * 512 + c;
  const float* p = pe + (size_t)s * 512 + c;
  const float* a = qa + (size_t)tt * 512 + c;
  float4 q0 = *(const float4*)q, q1 = *(const float4*)(q + 4);
  float4 p0 = *(const float4*)p, p1 = *(const float4*)(p + 4);
  float4 a0 = *(const float4*)a, a1 = *(const float4*)(a + 4);
  float qv[8] = {q0.x, q0.y, q0.z, q0.w, q1.x, q1.y, q1.z, q1.w};
  float pv[8] = {p0.x, p0.y, p0.z, p0.w, p1.x, p1.y, p1.z, p1.w};
  float av[8] = {a0.x, a0.y, a0.z, a0.w, a1.x, a1.y, a1.z, a1.w};
  short8 ox, oy;
#pragma unroll
  for (int i = 0; i < 8; ++i) {
    ox[i] = (short)f2bf(qv[i] + pv[i]);
    oy[i] = (short)f2bf(qv[i] + pv[i] + av[i]);
  }
  size_t base = (size_t)row * 512 + c;
  *(short8*)(x_b + base) = ox;
  *(short8*)(y_b + base) = oy;
}

// ---------------------------------------------------------------------------
// bf16 GEMM core (m97 structure): C[M,N] = act(A[M,K] @ Bt[N,K]^T + bias)
// 128x128 tile, BK=32, 256 thr. OUTM: 0 = bf16 row-major, 1 = f32 row-major,
// 2 = bf16 scatter into vT[b,h,dk,s].  (compile-time epilogue)
// ---------------------------------------------------------------------------
template <int ACT, int OUTM>
DEV void gemm_core(u16* As, u16* Bs,
                   const u16* __restrict__ A, const u16* __restrict__ Bt,
                   const float* __restrict__ bias, void* __restrict__ Cv,
                   int M, int N, int K, int bx, int by)
{
  const int lane = threadIdx.x & 63;
  const int w = threadIdx.x >> 6;
  const int wm = w >> 1, wn = w & 1;
  const int m0 = by * 128, n0 = bx * 128;

  const u16* pa[2];
  const u16* pb[2];
  u16* la[2];
  u16* lb[2];
#pragma unroll
  for (int i = 0; i < 2; ++i) {
    int tb = w * 2 + i;
    int r = tb * 16 + (lane >> 2);
    int ps = (lane & 3) ^ ((r >> 1) & 3);
    pa[i] = A + (size_t)(m0 + r) * K + ps * 8;
    int rb = n0 + r;
    rb = (rb < N) ? rb : (N - 1);
    pb[i] = Bt + (size_t)rb * K + ps * 8;
    la[i] = As + (tb * 64 + lane) * 8;
    lb[i] = Bs + (tb * 64 + lane) * 8;
  }
  const u16* ra[4];
  const u16* rbp[4];
#pragma unroll
  for (int i = 0; i < 4; ++i) {
    int r = wm * 64 + i * 16 + (lane & 15);
    ra[i] = As + (r * 4 + ((lane >> 4) ^ ((r >> 1) & 3))) * 8;
    int r2 = wn * 64 + i * 16 + (lane & 15);
    rbp[i] = Bs + (r2 * 4 + ((lane >> 4) ^ ((r2 >> 1) & 3))) * 8;
  }

  f32x4 acc[4][4];
#pragma unroll
  for (int a_ = 0; a_ < 4; ++a_)
#pragma unroll
    for (int b_ = 0; b_ < 4; ++b_)
#pragma unroll
      for (int i = 0; i < 4; ++i) acc[a_][b_][i] = 0.f;

  for (int k0 = 0; k0 < K; k0 += 32) {
    gl2l16(pa[0], la[0]);
    gl2l16(pa[1], la[1]);
    gl2l16(pb[0], lb[0]);
    gl2l16(pb[1], lb[1]);
    pa[0] += 32; pa[1] += 32; pb[0] += 32; pb[1] += 32;
    __syncthreads();
    short8 af[4], bf[4];
#pragma unroll
    for (int i = 0; i < 4; ++i) af[i] = *(const short8*)ra[i];
#pragma unroll
    for (int i = 0; i < 4; ++i) bf[i] = *(const short8*)rbp[i];
#pragma unroll
    for (int mt = 0; mt < 4; ++mt)
#pragma unroll
      for (int nt = 0; nt < 4; ++nt)
        acc[mt][nt] = MFMA16(af[mt], bf[nt], acc[mt][nt]);
    __syncthreads();
  }

  const int row0 = m0 + wm * 64, col0 = n0 + wn * 64;
#pragma unroll
  for (int mt = 0; mt < 4; ++mt) {
#pragma unroll
    for (int nt = 0; nt < 4; ++nt) {
      int c = col0 + nt * 16 + (lane & 15);
      int r = row0 + mt * 16 + (lane >> 4) * 4;
      if (c < N) {
        float bz = bias[c];
#pragma unroll
        for (int i = 0; i < 4; ++i) {
          float v = acc[mt][nt][i] + bz;
          if (ACT == 1) v = fmaxf(v, 0.f);
          int m = r + i;
          if (OUTM == 0) {
            ((u16*)Cv)[(size_t)m * N + c] = f2bf(v);
          } else if (OUTM == 1) {
            ((float*)Cv)[(size_t)m * N + c] = v;
          } else {  // vT[b][h][dk][s]: m=(b,s) local, c=(h,dk)
            size_t idx = ((((size_t)(m >> 9)) * 8 + (c >> 6)) * 64 + (c & 63)) * 512 + (m & 511);
            ((u16*)Cv)[idx] = f2bf(v);
          }
        }
      }
    }
  }
}

template <int ACT, int OUTM>
__global__ __launch_bounds__(256) void gemm_bt(
    const u16* __restrict__ A, const u16* __restrict__ Bt,
    const float* __restrict__ bias, void* __restrict__ Cv,
    int M, int N, int K)
{
  __shared__ alignas(16) u16 As[128 * 32];
  __shared__ alignas(16) u16 Bs[128 * 32];
  gemm_core<ACT, OUTM>(As, Bs, A, Bt, bias, Cv, M, N, K, blockIdx.x, blockIdx.y);
}

// fused K/V projection: z=0 -> x@Wk -> s_kq (OUTM 0); z=1 -> y@Wv -> vT (OUTM 2)
__global__ __launch_bounds__(256) void gemm_kv(
    const u16* __restrict__ A0, const u16* __restrict__ Bt0,
    const float* __restrict__ b0, void* __restrict__ C0,
    const u16* __restrict__ A1, const u16* __restrict__ Bt1,
    const float* __restrict__ b1, void* __restrict__ C1,
    int M, int N, int K)
{
  __shared__ alignas(16) u16 As[128 * 32];
  __shared__ alignas(16) u16 Bs[128 * 32];
  if (blockIdx.z == 0)
    gemm_core<0, 0>(As, Bs, A0, Bt0, b0, C0, M, N, K, blockIdx.x, blockIdx.y);
  else
    gemm_core<0, 2>(As, Bs, A1, Bt1, b1, C1, M, N, K, blockIdx.x, blockIdx.y);
}

// ---------------------------------------------------------------------------
// Flash attention, transposed scores. grid (qtile=4, h=8, b=NB), 256 thr.
// XCD-aware swizzle: linear block id l -> (t, bh) such that the 4 q-tiles of
// one (b,h) share l%8 (same XCD under round-robin dispatch) -> K/V L2 hits.
// Wave w owns q-cols [w*32, w*32+32). S^T = K Q^T via 16x16x32 (keys=M, q=N);
// C-layout: q = lane&15 (col), key = (lane>>4)*4+i (row). P^T stays in regs as
// 16x16x16 B-frags; O^T = V^T P^T with dk as M.
// K/V staged per chunk via global_load_lds (R0 style — no prefetch regs; at
// 128 VGPR occupancy is 4 blocks/CU and cross-block overlap hides the drain).
// Each chunk processed as TWO 64-key halves with their own online-softmax
// update (sc[4][2]/pf[4][2] live ranges). Live set ~116 < 128 -> no spill.
// Softmax math = R0 (scaled-domain mask/max, plain-subtract exp2 ->
// fully-masked rows give exp2(0)=1 benignly, neutralized by qg>0 guard).
// Epilogue bounces O^T through wave-private LDS (XOR swizzle) for coalesced
// short8 stores. LDS 32KB.
// ---------------------------------------------------------------------------
__global__ __launch_bounds__(256, 2) void attn_k(
    const u16* __restrict__ kq, const u16* __restrict__ vT, u16* __restrict__ o)
{
  __shared__ alignas(16) u16 Ks[128 * 64];
  __shared__ alignas(16) u16 Vs[64 * 128];
  // bijective swizzle of the linear id: bits[2:0]+bits[10:5] pick (b,h);
  // bits[4:3] pick q-tile -> same (b,h) stays on one XCD (l%8 fixed).
  const int l = blockIdx.x + 4 * (blockIdx.y + 8 * blockIdx.z);
  const int t = 3 - ((l >> 3) & 3);   // long q-tiles first -> better makespan
  const int bh = (l & 7) + 8 * (l >> 5);
  const int h = bh & 7, b = bh >> 3;
  const int lane = threadIdx.x & 63;
  const int w = threadIdx.x >> 6;
  const int q0 = t * 128;
  const size_t kq_base = ((size_t)b * 512) * 512 + h * 64;
  const float SC = 0.125f * 1.44269504089f;  // scale * log2(e): softmax in exp2 domain

  // stage Q tile [128 x 64] into Ks, then pull B-frags (q rows) to regs
#pragma unroll
  for (int i = 0; i < 4; ++i) {
    int tb = w * 4 + i;
    int r = tb * 8 + (lane >> 3);
    int ps = (lane & 7) ^ (r & 7);
    gl2l16(kq + kq_base + (size_t)(q0 + r) * 512 + ps * 8, Ks + (tb * 64 + lane) * 8);
  }
  __syncthreads();
  short8 qf[2][2];
#pragma unroll
  for (int nt = 0; nt < 2; ++nt)
#pragma unroll
    for (int ks = 0; ks < 2; ++ks) {
      int q = w * 32 + nt * 16 + (lane & 15);
      int ch = ks * 4 + (lane >> 4);
      qf[nt][ks] = *(const short8*)(Ks + (q * 8 + (ch ^ (q & 7))) * 8);
    }

  f32x4 of[4][2];  // [dk-tile][q-tile]; col=q=lane&15, row=dk=(lane>>4)*4+i
  float m_st[2] = {-1e30f, -1e30f}, l_st[2] = {0.f, 0.f};  // scaled domain
#pragma unroll
  for (int d = 0; d < 4; ++d)
#pragma unroll
    for (int nt = 0; nt < 2; ++nt)
#pragma unroll
      for (int i = 0; i < 4; ++i) of[d][nt][i] = 0.f;

  auto chunk = [&](int j, auto diagc) {
    constexpr bool DIAG = decltype(diagc)::value;
    // diagonal chunk: wave w needs keys < w*32+32 -> key-tiles mt < 2w+2
    const int MT = DIAG ? (2 * w + 2) : 8;
    const int k0 = j * 128;

    // two 64-key halves, each with its own online-softmax update: halves the
    // sc/pf live range (32+16 regs instead of 64+32) -> fits 128-reg target.
#pragma unroll
    for (int hh = 0; hh < 2; ++hh) {
      if (!DIAG || MT > hh * 4) {
        const int MTl = DIAG ? ((MT - hh * 4 < 4) ? MT - hh * 4 : 4) : 4;

        // S^T = K Q^T (this half's 4 key-tiles)
        f32x4 sc[4][2];
        __builtin_amdgcn_s_setprio(1);
#pragma unroll
        for (int mt = 0; mt < 4; ++mt)
          if (!DIAG || mt < MTl) {
#pragma unroll
            for (int nt = 0; nt < 2; ++nt)
#pragma unroll
              for (int i = 0; i < 4; ++i) sc[mt][nt][i] = 0.f;
#pragma unroll
            for (int ks = 0; ks < 2; ++ks) {
              int key = (hh * 4 + mt) * 16 + (lane & 15);
              int ch = ks * 4 + (lane >> 4);
              short8 kf = *(const short8*)(Ks + (key * 8 + (ch ^ (key & 7))) * 8);
              sc[mt][0] = MFMA16(kf, qf[0][ks], sc[mt][0]);
              sc[mt][1] = MFMA16(kf, qf[1][ks], sc[mt][1]);
            }
          }
        __builtin_amdgcn_s_setprio(0);

        // scale into log2 domain + strict causal mask (diag chunk only)
#pragma unroll
        for (int mt = 0; mt < 4; ++mt)
          if (!DIAG || mt < MTl) {
#pragma unroll
            for (int nt = 0; nt < 2; ++nt) {
              int qg = q0 + w * 32 + nt * 16 + (lane & 15);
#pragma unroll
              for (int i = 0; i < 4; ++i) {
                int kg = k0 + (hh * 4 + mt) * 16 + (lane >> 4) * 4 + i;
                float v = sc[mt][nt][i] * SC;
                if (DIAG && kg >= qg) v = -1e30f;
                sc[mt][nt][i] = v;
              }
            }
          }

        // online softmax (exp2 domain): per-lane scalar state (q = lane&15)
        short4v pf[4][2];
#pragma unroll
        for (int nt = 0; nt < 2; ++nt) {
          float mx = -1e30f;
#pragma unroll
          for (int mt = 0; mt < 4; ++mt)
            if (!DIAG || mt < MTl) {
#pragma unroll
              for (int i = 0; i < 4; ++i) mx = fmaxf(mx, sc[mt][nt][i]);
            }
          mx = fmaxf(mx, __shfl_xor(mx, 16));
          mx = fmaxf(mx, __shfl_xor(mx, 32));
          float mo = m_st[nt];
          float mn = fmaxf(mo, mx);
          float al = exp2f(mo - mn);
          float rs = 0.f;
#pragma unroll
          for (int mt = 0; mt < 4; ++mt)
            if (!DIAG || mt < MTl) {
#pragma unroll
              for (int i = 0; i < 4; ++i) {
                float pv = exp2f(sc[mt][nt][i] - mn);
                sc[mt][nt][i] = pv;
                rs += pv;
              }
            }
          rs += __shfl_xor(rs, 16);
          rs += __shfl_xor(rs, 32);
          m_st[nt] = mn;
          l_st[nt] = l_st[nt] * al + rs;
#pragma unroll
          for (int d = 0; d < 4; ++d)
#pragma unroll
            for (int i = 0; i < 4; ++i) of[d][nt][i] *= al;
          // pack P^T to bf16 16x16x16 B-frags (k = (lane>>4)*4+i)
#pragma unroll
          for (int mt = 0; mt < 4; ++mt)
            if (!DIAG || mt < MTl) {
#pragma unroll
              for (int i = 0; i < 4; ++i) pf[mt][nt][i] = (short)f2bf(sc[mt][nt][i]);
            }
        }

        // O^T += V^T P^T  (A = V^T frag: m=dk, k=key; 16x16x16)
        __builtin_amdgcn_s_setprio(1);
#pragma unroll
        for (int mt = 0; mt < 4; ++mt)
          if (!DIAG || mt < MTl) {
            int key4 = (hh * 4 + mt) * 16 + (lane >> 4) * 4;
#pragma unroll
            for (int d = 0; d < 4; ++d) {
              int dk = d * 16 + (lane & 15);
              short4v vf = *(const short4v*)(
                  Vs + (dk * 16 + ((key4 >> 3) ^ (dk & 15))) * 8 + (key4 & 7));
              of[d][0] = MFMA16X16(vf, pf[mt][0], of[d][0]);
              of[d][1] = MFMA16X16(vf, pf[mt][1], of[d][1]);
            }
          }
        __builtin_amdgcn_s_setprio(0);
      }
    }
  };

  for (int j = 0; j <= t; ++j) {
    const int k0 = j * 128;
    __syncthreads();  // qf/prior-iter LDS reads drained before restage
#pragma unroll
    for (int i = 0; i < 4; ++i) {  // K chunk [128 keys x 64]
      int tb = w * 4 + i;
      int r = tb * 8 + (lane >> 3);
      int ps = (lane & 7) ^ (r & 7);
      gl2l16(kq + kq_base + (size_t)(k0 + r) * 512 + ps * 8, Ks + (tb * 64 + lane) * 8);
    }
#pragma unroll
    for (int i = 0; i < 4; ++i) {  // V^T chunk [64 dk x 128 keys]
      int tb = w * 4 + i;
      int r = tb * 4 + (lane >> 4);
      int ps = (lane & 15) ^ (r & 15);
      gl2l16(vT + ((size_t)((b * 8 + h) * 64 + r)) * 512 + k0 + ps * 8, Vs + (tb * 64 + lane) * 8);
    }
    __syncthreads();
    if (j < t) {
      chunk(j, BoolC<false>{});
    } else {
      chunk(j, BoolC<true>{});
    }
  }

  // epilogue: O^T -> wave-private LDS (swizzled) -> coalesced row-major stores
  __syncthreads();  // all waves done reading Ks/Vs
  u16* Ws = Ks + w * 2048;  // 32 q-rows x 64 dk per wave
#pragma unroll
  for (int nt = 0; nt < 2; ++nt) {
    int qrow = nt * 16 + (lane & 15);
    int qg = q0 + w * 32 + qrow;
    float li = l_st[nt];
    float inv = (qg > 0 && li > 0.f) ? (1.f / li) : 0.f;
    int sw = (qrow & 7) * 8;
#pragma unroll
    for (int d = 0; d < 4; ++d)
#pragma unroll
      for (int i = 0; i < 4; ++i) {
        int dk = d * 16 + (lane >> 4) * 4 + i;
        Ws[qrow * 64 + (dk ^ sw)] = f2bf(of[d][nt][i] * inv);
      }
  }
  // wave-private: no barrier needed (lgkmcnt ordering within wave)
#pragma unroll
  for (int p = 0; p < 4; ++p) {
    int qrow = p * 8 + (lane >> 3);
    int c = lane & 7;
    short8 vv = *(const short8*)(Ws + qrow * 64 + ((c ^ (qrow & 7)) * 8));
    int qg = q0 + w * 32 + qrow;
    *(short8*)(o + ((size_t)b * 512 + qg) * 512 + h * 64 + c * 8) = vv;
  }
}

// ---------------------------------------------------------------------------
// LayerNorm(x + res); one wave per 512-col row; in-place safe.
// ---------------------------------------------------------------------------
__global__ __launch_bounds__(256) void ln_res(
    const u16* __restrict__ xin, const u16* __restrict__ res,
    const float* __restrict__ gam, const float* __restrict__ bet, u16* __restrict__ xout)
{
  const int row = blockIdx.x * 4 + (threadIdx.x >> 6);
  const int lane = threadIdx.x & 63;
  const size_t base = (size_t)row * 512 + lane * 8;
  short8 xv = *(const short8*)(xin + base);
  short8 rv = *(const short8*)(res + base);
  float v[8];
  float s = 0.f, s2 = 0.f;
#pragma unroll
  for (int i = 0; i < 8; ++i) {
    float a = bf2f((u16)xv[i]) + bf2f((u16)rv[i]);
    v[i] = a;
    s += a;
    s2 += a * a;
  }
#pragma unroll
  for (int d = 1; d < 64; d <<= 1) {
    s += __shfl_xor(s, d);
    s2 += __shfl_xor(s2, d);
  }
  float mean = s * (1.f / 512.f);
  float var = s2 * (1.f / 512.f) - mean * mean;
  float rstd = rsqrtf(var + 1e-5f);
  const int c = lane * 8;
  short8 ov;
#pragma unroll
  for (int i = 0; i < 8; ++i) {
    float ot = (v[i] - mean) * rstd * gam[c + i] + bet[c + i];
    ov[i] = (short)f2bf(ot);
  }
  *(short8*)(xout + base) = ov;
}

// ---------------------------------------------------------------------------
// concat [x, q_emb[q_data]] -> cat [rows,1024] bf16
// ---------------------------------------------------------------------------
__global__ __launch_bounds__(256) void concat2_k(
    const u16* __restrict__ x, const int* __restrict__ qd,
    const float* __restrict__ qemb, u16* __restrict__ cat)
{
  const int row = blockIdx.x * 4 + (threadIdx.x >> 6);
  const int lane = threadIdx.x & 63;
  *(short8*)(cat + (size_t)row * 1024 + lane * 8) =
      *(const short8*)(x + (size_t)row * 512 + lane * 8);
  const int idx = qd[row];
  const float* q = qemb + (size_t)idx * 512 + lane * 8;
  float4 q0 = *(const float4*)q, q1 = *(const float4*)(q + 4);
  float qv[8] = {q0.x, q0.y, q0.z, q0.w, q1.x, q1.y, q1.z, q1.w};
  short8 ov;
#pragma unroll
  for (int i = 0; i < 8; ++i) ov[i] = (short)f2bf(qv[i]);
  *(short8*)(cat + (size_t)row * 1024 + 512 + lane * 8) = ov;
}

// ---------------------------------------------------------------------------
extern "C" void kernel_launch(void* const* d_in, const int* in_sizes, int n_in,
                              void* d_out, int out_size, void* d_ws, size_t ws_size,
                              hipStream_t stream)
{
  const int* qd = (const int*)d_in[0];
  const int* tg = (const int*)d_in[1];
  const float* pe = (const float*)d_in[2];
  const float* qemb = (const float*)d_in[3];
  const float* qa = (const float*)d_in[4];
  const float* Wk = (const float*)d_in[5];
  const float* bk = (const float*)d_in[6];
  const float* Wv = (const float*)d_in[7];
  const float* bv = (const float*)d_in[8];
  const float* Wo = (const float*)d_in[9];
  const float* bo = (const float*)d_in[10];
  const float* g1 = (const float*)d_in[11];
  const float* be1 = (const float*)d_in[12];
  const float* W1 = (const float*)d_in[13];
  const float* b1 = (const float*)d_in[14];
  const float* W2 = (const float*)d_in[15];
  const float* b2 = (const float*)d_in[16];
  const float* g2 = (const float*)d_in[17];
  const float* be2 = (const float*)d_in[18];
  const float* Wo1 = (const float*)d_in[19];
  const float* bo1 = (const float*)d_in[20];
  const float* Wo2 = (const float*)d_in[21];
  const float* bo2 = (const float*)d_in[22];
  const float* Wo3 = (const float*)d_in[23];
  const float* bo3 = (const float*)d_in[24];
  float* out = (float*)d_out;

  const int BS = 64 * 512;  // 32768

  // batch-group chunking from ws_size (constant per process -> graph-safe)
  const size_t WU16 = 12266496ull;
  int NC = 1;
  {
    auto need = [&](int nc) -> size_t {
      size_t CMr = (size_t)BS / nc;
      size_t st = CMr < 8192 ? CMr : 8192;
      return 2ull * (WU16 + 2ull * BS * 512 + 3ull * CMr * 512 + st * 2048);
    };
    if (ws_size < need(1)) NC = 4;
    if (NC == 4 && ws_size < need(4)) NC = 8;
  }
  const int CM = BS / NC;
  const int MI = CM < 8192 ? CM : 8192;

  u16* p = (u16*)d_ws;
  u16* wkT = p;  p += 4 * 512 * 512;
  u16* wvT = p;  p += 4 * 512 * 512;
  u16* woT = p;  p += 4 * 512 * 512;
  u16* w1T = p;  p += 4 * 512 * 2048;
  u16* w2T = p;  p += 4 * 2048 * 512;
  u16* wo1T = p; p += 1024 * 512;
  u16* wo2T = p; p += 512 * 256;
  u16* wo3T = p; p += 300 * 256;
  u16* x_b = p;  p += (size_t)BS * 512;
  u16* y_b = p;  p += (size_t)BS * 512;
  u16* s_kq = p; p += (size_t)CM * 512;   // also head-cat first half
  u16* s_vT = p; p += (size_t)CM * 512;   // adjacent: cat = s_kq[CM x 1024]
  u16* s_o = p;  p += (size_t)CM * 512;
  u16* s_t = p;                            // MI x 2048 FFN / head scratch

  transpose_cvt<<<dim3(16, 16, 4), 256, 0, stream>>>(Wk, wkT, 512, 512);
  transpose_cvt<<<dim3(16, 16, 4), 256, 0, stream>>>(Wv, wvT, 512, 512);
  transpose_cvt<<<dim3(16, 16, 4), 256, 0, stream>>>(Wo, woT, 512, 512);
  transpose_cvt<<<dim3(64, 16, 4), 256, 0, stream>>>(W1, w1T, 512, 2048);
  transpose_cvt<<<dim3(16, 64, 4), 256, 0, stream>>>(W2, w2T, 2048, 512);
  transpose_cvt<<<dim3(16, 32, 1), 256, 0, stream>>>(Wo1, wo1T, 1024, 512);
  transpose_cvt<<<dim3(8, 16, 1), 256, 0, stream>>>(Wo2, wo2T, 512, 256);
  transpose_cvt<<<dim3(10, 8, 1), 256, 0, stream>>>(Wo3, wo3T, 256, 300);

  embed_k<<<BS / 4, 256, 0, stream>>>(qd, tg, pe, qemb, qa, x_b, y_b);

  for (int l = 0; l < 4; ++l) {
    const size_t lw = (size_t)l * 512 * 512;
    for (int cc = 0; cc < NC; ++cc) {
      const size_t R = (size_t)cc * CM;
      // fused q/k + v projections (kq_same=1)
      gemm_kv<<<dim3(4, CM / 128, 2), 256, 0, stream>>>(
          x_b + R * 512, wkT + lw, bk + l * 512, s_kq,
          y_b + R * 512, wvT + lw, bv + l * 512, s_vT, CM, 512, 512);
      attn_k<<<dim3(4, 8, CM / 512), 256, 0, stream>>>(s_kq, s_vT, s_o);
      gemm_bt<0, 0><<<dim3(4, CM / 128), 256, 0, stream>>>(
          s_o, woT + lw, bo + l * 512, s_kq, CM, 512, 512);
      ln_res<<<CM / 4, 256, 0, stream>>>(
          x_b + R * 512, s_kq, g1 + l * 512, be1 + l * 512, x_b + R * 512);
      for (int mc = 0; mc < CM; mc += MI) {
        gemm_bt<1, 0><<<dim3(16, MI / 128), 256, 0, stream>>>(
            x_b + (R + mc) * 512, w1T + (size_t)l * 512 * 2048, b1 + l * 2048,
            s_t, MI, 2048, 512);
        gemm_bt<0, 0><<<dim3(4, MI / 128), 256, 0, stream>>>(
            s_t, w2T + (size_t)l * 2048 * 512, b2 + l * 512,
            s_vT + (size_t)mc * 512, MI, 512, 2048);
      }
      ln_res<<<CM / 4, 256, 0, stream>>>(
          x_b + R * 512, s_vT, g2 + l * 512, be2 + l * 512, x_b + R * 512);
    }
  }

  for (int cc = 0; cc < NC; ++cc) {
    const size_t R = (size_t)cc * CM;
    concat2_k<<<CM / 4, 256, 0, stream>>>(x_b + R * 512, qd + R, qemb, s_kq);
    gemm_bt<1, 0><<<dim3(4, CM / 128), 256, 0, stream>>>(
        s_kq, wo1T, bo1, s_o, CM, 512, 1024);
    gemm_bt<1, 0><<<dim3(2, CM / 128), 256, 0, stream>>>(
        s_o, wo2T, bo2, s_t, CM, 256, 512);
    gemm_bt<0, 1><<<dim3(3, CM / 128), 256, 0, stream>>>(
        s_t, wo3T, bo3, out + R * 300, CM, 300, 256);
  }
}

// Round 6
// 2371.301 us; speedup vs baseline: 1.1086x; 1.0506x over previous
//
#include <hip/hip_runtime.h>

// simpleKT forward on gfx950: bf16 MFMA GEMMs + flash-style causal attention
// (transposed-scores formulation; P stays in registers; coalesced O epilogue;
//  XCD-aware block swizzle for K/V L2 locality).
// R6: two independent changes, separately attributable per-kernel:
//  (a) attn_k: P->bf16 pack via v_cvt_pk_bf16_f32 (RNE == f2bf on finite;
//      P in [0,1]) — 32 ops vs ~256 manual ops = -35% VALU. This is the
//      *safe* half of R1; the raw-domain exp2 fma (the diagnosed R1 bug)
//      stays reverted.
//  (b) gemm_core: BK=64 (As/Bs [128x64], 32KB LDS). Halves the per-K-step
//      barrier+vmcnt(0)-drain count (m97-structure's known ~20% stall).
//      Staging reuses attn's 8-slot XOR swizzle (ps = (lane&7)^(r&7), and
//      r&7 == lane>>3 for all tb -> slot uniform per wave). Occupancy
//      unchanged (VGPR-bound at 4 blocks/CU; LDS 32KB allows 5).
// R5 recap: attn spill eliminated (WRITE == 32MB == O exactly); kernel was
//  spill-bound R0-R4, never staging-latency-bound.
// B=64 S=512 D=512 H=8 DK=64 L=4 DFF=2048 NSK=300 FC1=512 FC2=256.
// ENVELOPE RULE: kernels use <=256 threads and <=32KB static LDS; no
// dynamic-LDS opt-in, no hipFuncSetAttribute.

typedef unsigned short u16;
typedef __attribute__((ext_vector_type(8))) short short8;   // 8 bf16 - 16x16x32 A/B frag
typedef __attribute__((ext_vector_type(4))) short short4v;  // 4 bf16 - 16x16x16 A/B frag
typedef __attribute__((ext_vector_type(4))) float f32x4;    // MFMA C/D frag

#define DEV __device__ __forceinline__

DEV float bf2f(u16 u) { return __uint_as_float(((unsigned int)u) << 16); }
DEV u16 f2bf(float f) {
  unsigned int u = __float_as_uint(f);
  u += 0x7FFFu + ((u >> 16) & 1u);
  return (u16)(u >> 16);
}

// v_cvt_pk_bf16_f32: low16 = bf16(lo), high16 = bf16(hi); RNE — bit-identical
// to f2bf for finite inputs.
DEV unsigned cvt_pk_bf16(float lo, float hi) {
  unsigned r;
  asm("v_cvt_pk_bf16_f32 %0, %1, %2" : "=v"(r) : "v"(lo), "v"(hi));
  return r;
}

template <bool V> struct BoolC { static constexpr bool value = V; };

DEV void gl2l16(const void* g, void* l) {
  __builtin_amdgcn_global_load_lds(
      (__attribute__((address_space(1))) void*)g,
      (__attribute__((address_space(3))) void*)l, 16, 0, 0);
}

#define MFMA16(a, b, c) __builtin_amdgcn_mfma_f32_16x16x32_bf16(a, b, c, 0, 0, 0)

// 16x16x16 bf16 MFMA (K=16: k = (lane>>4)*4+j — matches C-layout rows)
#if defined(__has_builtin)
#if __has_builtin(__builtin_amdgcn_mfma_f32_16x16x16bf16_1k)
#define MFMA16X16(a, b, c) __builtin_amdgcn_mfma_f32_16x16x16bf16_1k(a, b, c, 0, 0, 0)
#elif __has_builtin(__builtin_amdgcn_mfma_f32_16x16x16_bf16)
#define MFMA16X16(a, b, c) __builtin_amdgcn_mfma_f32_16x16x16_bf16(a, b, c, 0, 0, 0)
#endif
#endif
#ifndef MFMA16X16
DEV f32x4 mfma_16x16x16_bf16_asm(short4v a, short4v b, f32x4 c) {
  f32x4 d;
  asm("v_mfma_f32_16x16x16_bf16 %0, %1, %2, %3\n\ts_nop 7\n\ts_nop 3"
      : "=&v"(d) : "v"(a), "v"(b), "v"(c));
  return d;
}
#define MFMA16X16(a, b, c) mfma_16x16x16_bf16_asm(a, b, c)
#endif

// ---------------------------------------------------------------------------
// Weight convert+transpose: fp32 [K,N] (batched over z) -> bf16 [N,K]
// ---------------------------------------------------------------------------
__global__ __launch_bounds__(256) void transpose_cvt(
    const float* __restrict__ src, u16* __restrict__ dst, int K, int N)
{
  src += (size_t)blockIdx.z * K * N;
  dst += (size_t)blockIdx.z * K * N;
  __shared__ alignas(16) float tile[32][33];
  const int tx = threadIdx.x & 31, ty = threadIdx.x >> 5;
  const int n0 = blockIdx.x * 32, k0 = blockIdx.y * 32;
#pragma unroll
  for (int i = 0; i < 4; ++i) {
    int k = k0 + ty + i * 8, n = n0 + tx;
    if (k < K && n < N) tile[ty + i * 8][tx] = src[(size_t)k * N + n];
  }
  __syncthreads();
#pragma unroll
  for (int i = 0; i < 4; ++i) {
    int n = n0 + ty + i * 8, k = k0 + tx;
    if (n < N && k < K) dst[(size_t)n * K + k] = f2bf(tile[tx][ty + i * 8]);
  }
}

// ---------------------------------------------------------------------------
// Embedding: x = q_emb[q_data] + pe[s]; y = qa_emb[target] + q_emb[q_data] + pe[s]
// ---------------------------------------------------------------------------
__global__ __launch_bounds__(256) void embed_k(
    const int* __restrict__ qd, const int* __restrict__ tg,
    const float* __restrict__ pe, const float* __restrict__ qe, const float* __restrict__ qa,
    u16* __restrict__ x_b, u16* __restrict__ y_b)
{
  const int row = blockIdx.x * 4 + (threadIdx.x >> 6);
  const int lane = threadIdx.x & 63;
  const int s = row & 511;
  const int idx = qd[row];
  const int tt = tg[row];
  const int c = lane * 8;
  const float* q = qe + (size_t)idx * 512 + c;
  const float* p = pe + (size_t)s * 512 + c;
  const float* a = qa + (size_t)tt * 512 + c;
  float4 q0 = *(const float4*)q, q1 = *(const float4*)(q + 4);
  float4 p0 = *(const float4*)p, p1 = *(const float4*)(p + 4);
  float4 a0 = *(const float4*)a, a1 = *(const float4*)(a + 4);
  float qv[8] = {q0.x, q0.y, q0.z, q0.w, q1.x, q1.y, q1.z, q1.w};
  float pv[8] = {p0.x, p0.y, p0.z, p0.w, p1.x, p1.y, p1.z, p1.w};
  float av[8] = {a0.x, a0.y, a0.z, a0.w, a1.x, a1.y, a1.z, a1.w};
  short8 ox, oy;
#pragma unroll
  for (int i = 0; i < 8; ++i) {
    ox[i] = (short)f2bf(qv[i] + pv[i]);
    oy[i] = (short)f2bf(qv[i] + pv[i] + av[i]);
  }
  size_t base = (size_t)row * 512 + c;
  *(short8*)(x_b + base) = ox;
  *(short8*)(y_b + base) = oy;
}

// ---------------------------------------------------------------------------
// bf16 GEMM core: C[M,N] = act(A[M,K] @ Bt[N,K]^T + bias)
// 128x128 tile, BK=64, 256 thr. Staging: 16 sub-tiles of (8 rows x 64 cols),
// wave w owns tb = w*4+i; slot swizzle ps = (lane&7)^(r&7) with r&7 == lane>>3
// (uniform across tb). Per K-step: 8 gl2l16, one barrier pair, 2x16 MFMA.
// OUTM: 0 = bf16 row-major, 1 = f32 row-major, 2 = bf16 scatter vT[b,h,dk,s].
// ---------------------------------------------------------------------------
template <int ACT, int OUTM>
DEV void gemm_core(u16* As, u16* Bs,
                   const u16* __restrict__ A, const u16* __restrict__ Bt,
                   const float* __restrict__ bias, void* __restrict__ Cv,
                   int M, int N, int K, int bx, int by)
{
  const int lane = threadIdx.x & 63;
  const int w = threadIdx.x >> 6;
  const int wm = w >> 1, wn = w & 1;
  const int m0 = by * 128, n0 = bx * 128;

  // staging addresses: rows rs_+8i (i<4), slot ps_ (8 u16 = 16B)
  const int rs_ = w * 32 + (lane >> 3);
  const int ps_ = (lane & 7) ^ (lane >> 3);   // r&7 == lane>>3 for all tb
  const u16* pa = A + (size_t)(m0 + rs_) * K + ps_ * 8;
  const u16* pb[4];
#pragma unroll
  for (int i = 0; i < 4; ++i) {
    int rb = n0 + rs_ + i * 8;
    rb = (rb < N) ? rb : (N - 1);
    pb[i] = Bt + (size_t)rb * K + ps_ * 8;
  }
  u16* la = As + (w * 4 * 64 + lane) * 8;
  u16* lb = Bs + (w * 4 * 64 + lane) * 8;

  f32x4 acc[4][4];
#pragma unroll
  for (int a_ = 0; a_ < 4; ++a_)
#pragma unroll
    for (int b_ = 0; b_ < 4; ++b_)
#pragma unroll
      for (int i = 0; i < 4; ++i) acc[a_][b_][i] = 0.f;

  for (int k0 = 0; k0 < K; k0 += 64) {
#pragma unroll
    for (int i = 0; i < 4; ++i) gl2l16(pa + (size_t)i * 8 * K, la + i * 64 * 8);
#pragma unroll
    for (int i = 0; i < 4; ++i) gl2l16(pb[i], lb + i * 64 * 8);
    pa += 64;
#pragma unroll
    for (int i = 0; i < 4; ++i) pb[i] += 64;
    __syncthreads();
#pragma unroll
    for (int ks = 0; ks < 2; ++ks) {
      short8 af[4], bf[4];
#pragma unroll
      for (int i = 0; i < 4; ++i) {
        int r = wm * 64 + i * 16 + (lane & 15);
        af[i] = *(const short8*)(As + (r * 8 + ((ks * 4 + (lane >> 4)) ^ (r & 7))) * 8);
        int r2 = wn * 64 + i * 16 + (lane & 15);
        bf[i] = *(const short8*)(Bs + (r2 * 8 + ((ks * 4 + (lane >> 4)) ^ (r2 & 7))) * 8);
      }
#pragma unroll
      for (int mt = 0; mt < 4; ++mt)
#pragma unroll
        for (int nt = 0; nt < 4; ++nt)
          acc[mt][nt] = MFMA16(af[mt], bf[nt], acc[mt][nt]);
    }
    __syncthreads();
  }

  const int row0 = m0 + wm * 64, col0 = n0 + wn * 64;
#pragma unroll
  for (int mt = 0; mt < 4; ++mt) {
#pragma unroll
    for (int nt = 0; nt < 4; ++nt) {
      int c = col0 + nt * 16 + (lane & 15);
      int r = row0 + mt * 16 + (lane >> 4) * 4;
      if (c < N) {
        float bz = bias[c];
#pragma unroll
        for (int i = 0; i < 4; ++i) {
          float v = acc[mt][nt][i] + bz;
          if (ACT == 1) v = fmaxf(v, 0.f);
          int m = r + i;
          if (OUTM == 0) {
            ((u16*)Cv)[(size_t)m * N + c] = f2bf(v);
          } else if (OUTM == 1) {
            ((float*)Cv)[(size_t)m * N + c] = v;
          } else {  // vT[b][h][dk][s]: m=(b,s) local, c=(h,dk)
            size_t idx = ((((size_t)(m >> 9)) * 8 + (c >> 6)) * 64 + (c & 63)) * 512 + (m & 511);
            ((u16*)Cv)[idx] = f2bf(v);
          }
        }
      }
    }
  }
}

template <int ACT, int OUTM>
__global__ __launch_bounds__(256) void gemm_bt(
    const u16* __restrict__ A, const u16* __restrict__ Bt,
    const float* __restrict__ bias, void* __restrict__ Cv,
    int M, int N, int K)
{
  __shared__ alignas(16) u16 As[128 * 64];
  __shared__ alignas(16) u16 Bs[128 * 64];
  gemm_core<ACT, OUTM>(As, Bs, A, Bt, bias, Cv, M, N, K, blockIdx.x, blockIdx.y);
}

// fused K/V projection: z=0 -> x@Wk -> s_kq (OUTM 0); z=1 -> y@Wv -> vT (OUTM 2)
__global__ __launch_bounds__(256) void gemm_kv(
    const u16* __restrict__ A0, const u16* __restrict__ Bt0,
    const float* __restrict__ b0, void* __restrict__ C0,
    const u16* __restrict__ A1, const u16* __restrict__ Bt1,
    const float* __restrict__ b1, void* __restrict__ C1,
    int M, int N, int K)
{
  __shared__ alignas(16) u16 As[128 * 64];
  __shared__ alignas(16) u16 Bs[128 * 64];
  if (blockIdx.z == 0)
    gemm_core<0, 0>(As, Bs, A0, Bt0, b0, C0, M, N, K, blockIdx.x, blockIdx.y);
  else
    gemm_core<0, 2>(As, Bs, A1, Bt1, b1, C1, M, N, K, blockIdx.x, blockIdx.y);
}

// ---------------------------------------------------------------------------
// Flash attention, transposed scores. grid (qtile=4, h=8, b=NB), 256 thr.
// XCD-aware swizzle: linear block id l -> (t, bh) such that the 4 q-tiles of
// one (b,h) share l%8 (same XCD under round-robin dispatch) -> K/V L2 hits.
// Wave w owns q-cols [w*32, w*32+32). S^T = K Q^T via 16x16x32 (keys=M, q=N);
// C-layout: q = lane&15 (col), key = (lane>>4)*4+i (row). P^T stays in regs as
// 16x16x16 B-frags; O^T = V^T P^T with dk as M.
// K/V staged per chunk via global_load_lds; each chunk processed as TWO
// 64-key halves with their own online-softmax update (live set fits 128-reg
// target, no spill — R5 verified WRITE == 32MB == O exactly).
// Softmax math = R0 (scaled-domain mask/max, plain-subtract exp2); pack
// P->bf16 via v_cvt_pk_bf16_f32 (R6: RNE == f2bf on finite; -35% VALU).
// Epilogue bounces O^T through wave-private LDS (XOR swizzle) for coalesced
// short8 stores. LDS 32KB.
// ---------------------------------------------------------------------------
__global__ __launch_bounds__(256, 2) void attn_k(
    const u16* __restrict__ kq, const u16* __restrict__ vT, u16* __restrict__ o)
{
  __shared__ alignas(16) u16 Ks[128 * 64];
  __shared__ alignas(16) u16 Vs[64 * 128];
  // bijective swizzle of the linear id: bits[2:0]+bits[10:5] pick (b,h);
  // bits[4:3] pick q-tile -> same (b,h) stays on one XCD (l%8 fixed).
  const int l = blockIdx.x + 4 * (blockIdx.y + 8 * blockIdx.z);
  const int t = 3 - ((l >> 3) & 3);   // long q-tiles first -> better makespan
  const int bh = (l & 7) + 8 * (l >> 5);
  const int h = bh & 7, b = bh >> 3;
  const int lane = threadIdx.x & 63;
  const int w = threadIdx.x >> 6;
  const int q0 = t * 128;
  const size_t kq_base = ((size_t)b * 512) * 512 + h * 64;
  const float SC = 0.125f * 1.44269504089f;  // scale * log2(e): softmax in exp2 domain

  // stage Q tile [128 x 64] into Ks, then pull B-frags (q rows) to regs
#pragma unroll
  for (int i = 0; i < 4; ++i) {
    int tb = w * 4 + i;
    int r = tb * 8 + (lane >> 3);
    int ps = (lane & 7) ^ (r & 7);
    gl2l16(kq + kq_base + (size_t)(q0 + r) * 512 + ps * 8, Ks + (tb * 64 + lane) * 8);
  }
  __syncthreads();
  short8 qf[2][2];
#pragma unroll
  for (int nt = 0; nt < 2; ++nt)
#pragma unroll
    for (int ks = 0; ks < 2; ++ks) {
      int q = w * 32 + nt * 16 + (lane & 15);
      int ch = ks * 4 + (lane >> 4);
      qf[nt][ks] = *(const short8*)(Ks + (q * 8 + (ch ^ (q & 7))) * 8);
    }

  f32x4 of[4][2];  // [dk-tile][q-tile]; col=q=lane&15, row=dk=(lane>>4)*4+i
  float m_st[2] = {-1e30f, -1e30f}, l_st[2] = {0.f, 0.f};  // scaled domain
#pragma unroll
  for (int d = 0; d < 4; ++d)
#pragma unroll
    for (int nt = 0; nt < 2; ++nt)
#pragma unroll
      for (int i = 0; i < 4; ++i) of[d][nt][i] = 0.f;

  auto chunk = [&](int j, auto diagc) {
    constexpr bool DIAG = decltype(diagc)::value;
    // diagonal chunk: wave w needs keys < w*32+32 -> key-tiles mt < 2w+2
    const int MT = DIAG ? (2 * w + 2) : 8;
    const int k0 = j * 128;

    // two 64-key halves, each with its own online-softmax update: halves the
    // sc/pf live range (32+16 regs instead of 64+32) -> fits 128-reg target.
#pragma unroll
    for (int hh = 0; hh < 2; ++hh) {
      if (!DIAG || MT > hh * 4) {
        const int MTl = DIAG ? ((MT - hh * 4 < 4) ? MT - hh * 4 : 4) : 4;

        // S^T = K Q^T (this half's 4 key-tiles)
        f32x4 sc[4][2];
        __builtin_amdgcn_s_setprio(1);
#pragma unroll
        for (int mt = 0; mt < 4; ++mt)
          if (!DIAG || mt < MTl) {
#pragma unroll
            for (int nt = 0; nt < 2; ++nt)
#pragma unroll
              for (int i = 0; i < 4; ++i) sc[mt][nt][i] = 0.f;
#pragma unroll
            for (int ks = 0; ks < 2; ++ks) {
              int key = (hh * 4 + mt) * 16 + (lane & 15);
              int ch = ks * 4 + (lane >> 4);
              short8 kf = *(const short8*)(Ks + (key * 8 + (ch ^ (key & 7))) * 8);
              sc[mt][0] = MFMA16(kf, qf[0][ks], sc[mt][0]);
              sc[mt][1] = MFMA16(kf, qf[1][ks], sc[mt][1]);
            }
          }
        __builtin_amdgcn_s_setprio(0);

        // scale into log2 domain + strict causal mask (diag chunk only)
#pragma unroll
        for (int mt = 0; mt < 4; ++mt)
          if (!DIAG || mt < MTl) {
#pragma unroll
            for (int nt = 0; nt < 2; ++nt) {
              int qg = q0 + w * 32 + nt * 16 + (lane & 15);
#pragma unroll
              for (int i = 0; i < 4; ++i) {
                int kg = k0 + (hh * 4 + mt) * 16 + (lane >> 4) * 4 + i;
                float v = sc[mt][nt][i] * SC;
                if (DIAG && kg >= qg) v = -1e30f;
                sc[mt][nt][i] = v;
              }
            }
          }

        // online softmax (exp2 domain): per-lane scalar state (q = lane&15)
        short4v pf[4][2];
#pragma unroll
        for (int nt = 0; nt < 2; ++nt) {
          float mx = -1e30f;
#pragma unroll
          for (int mt = 0; mt < 4; ++mt)
            if (!DIAG || mt < MTl) {
#pragma unroll
              for (int i = 0; i < 4; ++i) mx = fmaxf(mx, sc[mt][nt][i]);
            }
          mx = fmaxf(mx, __shfl_xor(mx, 16));
          mx = fmaxf(mx, __shfl_xor(mx, 32));
          float mo = m_st[nt];
          float mn = fmaxf(mo, mx);
          float al = exp2f(mo - mn);
          float rs = 0.f;
#pragma unroll
          for (int mt = 0; mt < 4; ++mt)
            if (!DIAG || mt < MTl) {
#pragma unroll
              for (int i = 0; i < 4; ++i) {
                float pv = exp2f(sc[mt][nt][i] - mn);
                sc[mt][nt][i] = pv;
                rs += pv;
              }
            }
          rs += __shfl_xor(rs, 16);
          rs += __shfl_xor(rs, 32);
          m_st[nt] = mn;
          l_st[nt] = l_st[nt] * al + rs;
#pragma unroll
          for (int d = 0; d < 4; ++d)
#pragma unroll
            for (int i = 0; i < 4; ++i) of[d][nt][i] *= al;
          // pack P^T to bf16 16x16x16 B-frags (k = (lane>>4)*4+i) via cvt_pk
#pragma unroll
          for (int mt = 0; mt < 4; ++mt)
            if (!DIAG || mt < MTl) {
              union { unsigned u[2]; short4v s; } cv;
              cv.u[0] = cvt_pk_bf16(sc[mt][nt][0], sc[mt][nt][1]);
              cv.u[1] = cvt_pk_bf16(sc[mt][nt][2], sc[mt][nt][3]);
              pf[mt][nt] = cv.s;
            }
        }

        // O^T += V^T P^T  (A = V^T frag: m=dk, k=key; 16x16x16)
        __builtin_amdgcn_s_setprio(1);
#pragma unroll
        for (int mt = 0; mt < 4; ++mt)
          if (!DIAG || mt < MTl) {
            int key4 = (hh * 4 + mt) * 16 + (lane >> 4) * 4;
#pragma unroll
            for (int d = 0; d < 4; ++d) {
              int dk = d * 16 + (lane & 15);
              short4v vf = *(const short4v*)(
                  Vs + (dk * 16 + ((key4 >> 3) ^ (dk & 15))) * 8 + (key4 & 7));
              of[d][0] = MFMA16X16(vf, pf[mt][0], of[d][0]);
              of[d][1] = MFMA16X16(vf, pf[mt][1], of[d][1]);
            }
          }
        __builtin_amdgcn_s_setprio(0);
      }
    }
  };

  for (int j = 0; j <= t; ++j) {
    const int k0 = j * 128;
    __syncthreads();  // qf/prior-iter LDS reads drained before restage
#pragma unroll
    for (int i = 0; i < 4; ++i) {  // K chunk [128 keys x 64]
      int tb = w * 4 + i;
      int r = tb * 8 + (lane >> 3);
      int ps = (lane & 7) ^ (r & 7);
      gl2l16(kq + kq_base + (size_t)(k0 + r) * 512 + ps * 8, Ks + (tb * 64 + lane) * 8);
    }
#pragma unroll
    for (int i = 0; i < 4; ++i) {  // V^T chunk [64 dk x 128 keys]
      int tb = w * 4 + i;
      int r = tb * 4 + (lane >> 4);
      int ps = (lane & 15) ^ (r & 15);
      gl2l16(vT + ((size_t)((b * 8 + h) * 64 + r)) * 512 + k0 + ps * 8, Vs + (tb * 64 + lane) * 8);
    }
    __syncthreads();
    if (j < t) {
      chunk(j, BoolC<false>{});
    } else {
      chunk(j, BoolC<true>{});
    }
  }

  // epilogue: O^T -> wave-private LDS (swizzled) -> coalesced row-major stores
  __syncthreads();  // all waves done reading Ks/Vs
  u16* Ws = Ks + w * 2048;  // 32 q-rows x 64 dk per wave
#pragma unroll
  for (int nt = 0; nt < 2; ++nt) {
    int qrow = nt * 16 + (lane & 15);
    int qg = q0 + w * 32 + qrow;
    float li = l_st[nt];
    float inv = (qg > 0 && li > 0.f) ? (1.f / li) : 0.f;
    int sw = (qrow & 7) * 8;
#pragma unroll
    for (int d = 0; d < 4; ++d)
#pragma unroll
      for (int i = 0; i < 4; ++i) {
        int dk = d * 16 + (lane >> 4) * 4 + i;
        Ws[qrow * 64 + (dk ^ sw)] = f2bf(of[d][nt][i] * inv);
      }
  }
  // wave-private: no barrier needed (lgkmcnt ordering within wave)
#pragma unroll
  for (int p = 0; p < 4; ++p) {
    int qrow = p * 8 + (lane >> 3);
    int c = lane & 7;
    short8 vv = *(const short8*)(Ws + qrow * 64 + ((c ^ (qrow & 7)) * 8));
    int qg = q0 + w * 32 + qrow;
    *(short8*)(o + ((size_t)b * 512 + qg) * 512 + h * 64 + c * 8) = vv;
  }
}

// ---------------------------------------------------------------------------
// LayerNorm(x + res); one wave per 512-col row; in-place safe.
// ---------------------------------------------------------------------------
__global__ __launch_bounds__(256) void ln_res(
    const u16* __restrict__ xin, const u16* __restrict__ res,
    const float* __restrict__ gam, const float* __restrict__ bet, u16* __restrict__ xout)
{
  const int row = blockIdx.x * 4 + (threadIdx.x >> 6);
  const int lane = threadIdx.x & 63;
  const size_t base = (size_t)row * 512 + lane * 8;
  short8 xv = *(const short8*)(xin + base);
  short8 rv = *(const short8*)(res + base);
  float v[8];
  float s = 0.f, s2 = 0.f;
#pragma unroll
  for (int i = 0; i < 8; ++i) {
    float a = bf2f((u16)xv[i]) + bf2f((u16)rv[i]);
    v[i] = a;
    s += a;
    s2 += a * a;
  }
#pragma unroll
  for (int d = 1; d < 64; d <<= 1) {
    s += __shfl_xor(s, d);
    s2 += __shfl_xor(s2, d);
  }
  float mean = s * (1.f / 512.f);
  float var = s2 * (1.f / 512.f) - mean * mean;
  float rstd = rsqrtf(var + 1e-5f);
  const int c = lane * 8;
  short8 ov;
#pragma unroll
  for (int i = 0; i < 8; ++i) {
    float ot = (v[i] - mean) * rstd * gam[c + i] + bet[c + i];
    ov[i] = (short)f2bf(ot);
  }
  *(short8*)(xout + base) = ov;
}

// ---------------------------------------------------------------------------
// concat [x, q_emb[q_data]] -> cat [rows,1024] bf16
// ---------------------------------------------------------------------------
__global__ __launch_bounds__(256) void concat2_k(
    const u16* __restrict__ x, const int* __restrict__ qd,
    const float* __restrict__ qemb, u16* __restrict__ cat)
{
  const int row = blockIdx.x * 4 + (threadIdx.x >> 6);
  const int lane = threadIdx.x & 63;
  *(short8*)(cat + (size_t)row * 1024 + lane * 8) =
      *(const short8*)(x + (size_t)row * 512 + lane * 8);
  const int idx = qd[row];
  const float* q = qemb + (size_t)idx * 512 + lane * 8;
  float4 q0 = *(const float4*)q, q1 = *(const float4*)(q + 4);
  float qv[8] = {q0.x, q0.y, q0.z, q0.w, q1.x, q1.y, q1.z, q1.w};
  short8 ov;
#pragma unroll
  for (int i = 0; i < 8; ++i) ov[i] = (short)f2bf(qv[i]);
  *(short8*)(cat + (size_t)row * 1024 + 512 + lane * 8) = ov;
}

// ---------------------------------------------------------------------------
extern "C" void kernel_launch(void* const* d_in, const int* in_sizes, int n_in,
                              void* d_out, int out_size, void* d_ws, size_t ws_size,
                              hipStream_t stream)
{
  const int* qd = (const int*)d_in[0];
  const int* tg = (const int*)d_in[1];
  const float* pe = (const float*)d_in[2];
  const float* qemb = (const float*)d_in[3];
  const float* qa = (const float*)d_in[4];
  const float* Wk = (const float*)d_in[5];
  const float* bk = (const float*)d_in[6];
  const float* Wv = (const float*)d_in[7];
  const float* bv = (const float*)d_in[8];
  const float* Wo = (const float*)d_in[9];
  const float* bo = (const float*)d_in[10];
  const float* g1 = (const float*)d_in[11];
  const float* be1 = (const float*)d_in[12];
  const float* W1 = (const float*)d_in[13];
  const float* b1 = (const float*)d_in[14];
  const float* W2 = (const float*)d_in[15];
  const float* b2 = (const float*)d_in[16];
  const float* g2 = (const float*)d_in[17];
  const float* be2 = (const float*)d_in[18];
  const float* Wo1 = (const float*)d_in[19];
  const float* bo1 = (const float*)d_in[20];
  const float* Wo2 = (const float*)d_in[21];
  const float* bo2 = (const float*)d_in[22];
  const float* Wo3 = (const float*)d_in[23];
  const float* bo3 = (const float*)d_in[24];
  float* out = (float*)d_out;

  const int BS = 64 * 512;  // 32768

  // batch-group chunking from ws_size (constant per process -> graph-safe)
  const size_t WU16 = 12266496ull;
  int NC = 1;
  {
    auto need = [&](int nc) -> size_t {
      size_t CMr = (size_t)BS / nc;
      size_t st = CMr < 8192 ? CMr : 8192;
      return 2ull * (WU16 + 2ull * BS * 512 + 3ull * CMr * 512 + st * 2048);
    };
    if (ws_size < need(1)) NC = 4;
    if (NC == 4 && ws_size < need(4)) NC = 8;
  }
  const int CM = BS / NC;
  const int MI = CM < 8192 ? CM : 8192;

  u16* p = (u16*)d_ws;
  u16* wkT = p;  p += 4 * 512 * 512;
  u16* wvT = p;  p += 4 * 512 * 512;
  u16* woT = p;  p += 4 * 512 * 512;
  u16* w1T = p;  p += 4 * 512 * 2048;
  u16* w2T = p;  p += 4 * 2048 * 512;
  u16* wo1T = p; p += 1024 * 512;
  u16* wo2T = p; p += 512 * 256;
  u16* wo3T = p; p += 300 * 256;
  u16* x_b = p;  p += (size_t)BS * 512;
  u16* y_b = p;  p += (size_t)BS * 512;
  u16* s_kq = p; p += (size_t)CM * 512;   // also head-cat first half
  u16* s_vT = p; p += (size_t)CM * 512;   // adjacent: cat = s_kq[CM x 1024]
  u16* s_o = p;  p += (size_t)CM * 512;
  u16* s_t = p;                            // MI x 2048 FFN / head scratch

  transpose_cvt<<<dim3(16, 16, 4), 256, 0, stream>>>(Wk, wkT, 512, 512);
  transpose_cvt<<<dim3(16, 16, 4), 256, 0, stream>>>(Wv, wvT, 512, 512);
  transpose_cvt<<<dim3(16, 16, 4), 256, 0, stream>>>(Wo, woT, 512, 512);
  transpose_cvt<<<dim3(64, 16, 4), 256, 0, stream>>>(W1, w1T, 512, 2048);
  transpose_cvt<<<dim3(16, 64, 4), 256, 0, stream>>>(W2, w2T, 2048, 512);
  transpose_cvt<<<dim3(16, 32, 1), 256, 0, stream>>>(Wo1, wo1T, 1024, 512);
  transpose_cvt<<<dim3(8, 16, 1), 256, 0, stream>>>(Wo2, wo2T, 512, 256);
  transpose_cvt<<<dim3(10, 8, 1), 256, 0, stream>>>(Wo3, wo3T, 256, 300);

  embed_k<<<BS / 4, 256, 0, stream>>>(qd, tg, pe, qemb, qa, x_b, y_b);

  for (int l = 0; l < 4; ++l) {
    const size_t lw = (size_t)l * 512 * 512;
    for (int cc = 0; cc < NC; ++cc) {
      const size_t R = (size_t)cc * CM;
      // fused q/k + v projections (kq_same=1)
      gemm_kv<<<dim3(4, CM / 128, 2), 256, 0, stream>>>(
          x_b + R * 512, wkT + lw, bk + l * 512, s_kq,
          y_b + R * 512, wvT + lw, bv + l * 512, s_vT, CM, 512, 512);
      attn_k<<<dim3(4, 8, CM / 512), 256, 0, stream>>>(s_kq, s_vT, s_o);
      gemm_bt<0, 0><<<dim3(4, CM / 128), 256, 0, stream>>>(
          s_o, woT + lw, bo + l * 512, s_kq, CM, 512, 512);
      ln_res<<<CM / 4, 256, 0, stream>>>(
          x_b + R * 512, s_kq, g1 + l * 512, be1 + l * 512, x_b + R * 512);
      for (int mc = 0; mc < CM; mc += MI) {
        gemm_bt<1, 0><<<dim3(16, MI / 128), 256, 0, stream>>>(
            x_b + (R + mc) * 512, w1T + (size_t)l * 512 * 2048, b1 + l * 2048,
            s_t, MI, 2048, 512);
        gemm_bt<0, 0><<<dim3(4, MI / 128), 256, 0, stream>>>(
            s_t, w2T + (size_t)l * 2048 * 512, b2 + l * 512,
            s_vT + (size_t)mc * 512, MI, 512, 2048);
      }
      ln_res<<<CM / 4, 256, 0, stream>>>(
          x_b + R * 512, s_vT, g2 + l * 512, be2 + l * 512, x_b + R * 512);
    }
  }

  for (int cc = 0; cc < NC; ++cc) {
    const size_t R = (size_t)cc * CM;
    concat2_k<<<CM / 4, 256, 0, stream>>>(x_b + R * 512, qd + R, qemb, s_kq);
    gemm_bt<1, 0><<<dim3(4, CM / 128), 256, 0, stream>>>(
        s_kq, wo1T, bo1, s_o, CM, 512, 1024);
    gemm_bt<1, 0><<<dim3(2, CM / 128), 256, 0, stream>>>(
        s_o, wo2T, bo2, s_t, CM, 256, 512);
    gemm_bt<0, 1><<<dim3(3, CM / 128), 256, 0, stream>>>(
        s_t, wo3T, bo3, out + R * 300, CM, 300, 256);
  }
}